// Round 7
// baseline (296.434 us; speedup 1.0000x reference)
//
#include <hip/hip_runtime.h>

#define SS 8
#define NN 5000
#define NNSQ 25000000
#define DD 128
#define RB 8          // rows per block
#define JS 4          // column splits (partials)
#define JT 128        // tile columns
#define TPB 10        // tiles per block
#define RG 625        // row groups

typedef float f4 __attribute__((ext_vector_type(4)));

typedef const __attribute__((address_space(1))) void glb_void;
typedef __attribute__((address_space(3))) void lds_void;

__device__ __forceinline__ void gld_lds16(const void* g, void* l) {
    __builtin_amdgcn_global_load_lds((glb_void*)g, (lds_void*)l, 16, 0, 0);
}

#define VMCNT8 asm volatile("s_waitcnt vmcnt(8)" ::: "memory")
#define VMCNT0 asm volatile("s_waitcnt vmcnt(0)" ::: "memory")
#define SB0    __builtin_amdgcn_sched_barrier(0)

// Wave-decoupled: each wave owns a 32-col j-window of the 128-col tile.
// Staging, q-compute, and Phase B all stay inside the wave -> no barriers.
__global__ __launch_bounds__(256, 2)
void diffuse_spmm(const float* __restrict__ theta,
                  const float* __restrict__ Tm,
                  const float* __restrict__ x,
                  const float* __restrict__ am,
                  float* __restrict__ ws)
{
    __shared__ float stg[2][SS][4][RB * 32];   // 64 KB; [buf][slice][wave][row8*col32]
    __shared__ float qld[4][RB * 32];          // 4 KB;  [wave][row8*col32]

    const int t    = threadIdx.x;
    const int wid  = t >> 6;
    const int lane = t & 63;
    const int rg   = blockIdx.x % RG;
    const int js   = blockIdx.x / RG;
    const int i0   = rg * RB;
    const int tile0 = js * TPB;
    const int jw   = wid << 5;            // wave's col-window start within tile

    // staging / q-compute lane mapping (matches DMA's lane->addr layout)
    const int qrow = lane >> 3;           // 0..7
    const int qcol = (lane & 7) << 2;     // 0,4,...,28
    const int lb   = (qrow << 5) + qcol;  // offset in [row8*col32]
    // Phase B lane mapping
    const int d0   = (lane & 31) << 2;    // d-quad
    const int jh   = lane >> 5;           // 0/1: 16-col half of the window

    float th[SS];
#pragma unroll
    for (int s = 0; s < SS; ++s) th[s] = theta[s];

    // DMA tile (rel m) T cols [jw, jw+32) x rows [i0, i0+8) into stg[m&1][*][wid].
    // LDS dest wave-uniform; lane ell covers [ell>>3][(ell&7)*4] (1 KB contiguous).
    auto stage_dma = [&](int m) {
        const int jg = (tile0 + m) * JT + jw + qcol;
        if (jg < NN) {
            const size_t goff = (size_t)(i0 + qrow) * NN + jg;
#pragma unroll
            for (int s = 0; s < SS; ++s)
                gld_lds16(Tm + (size_t)s * NNSQ + goff, &stg[m & 1][s][wid][0]);
        }
    };

    auto aload = [&](int m) -> f4 {
        const int jg = (tile0 + m) * JT + jw + qcol;
        f4 v = (f4)(0.0f);
        if (jg < NN) v = *(const f4*)(am + (size_t)(i0 + qrow) * NN + jg);
        return v;
    };

    // q for tile m -> qld[wid]; reads only own-wave staged data
    auto qcompute = [&](int m, f4 sa) {
        const int jg = (tile0 + m) * JT + jw + qcol;
        f4 ssum = (*(const f4*)&stg[m & 1][0][wid][lb]) * th[0];
#pragma unroll
        for (int s = 1; s < SS; ++s)
            ssum += (*(const f4*)&stg[m & 1][s][wid][lb]) * th[s];
        f4 q = sa * ssum;
        if (jg >= NN) q = (f4)(0.0f);     // mask stale LDS on ragged tile
        *(f4*)&qld[wid][lb] = q;
    };

    f4 acc[RB];
#pragma unroll
    for (int r = 0; r < RB; ++r) acc[r] = (f4)(0.0f);

    // ---- prologue: [dma0(8)] [a0(1)] [dma1(8)] -> wait oldest 9 -> q(0) ----
    stage_dma(0);
    SB0;
    f4 sa = aload(0);
    SB0;
    stage_dma(1);
    SB0;
    VMCNT8;                                // dma0 + a0 done; dma1 in flight
    SB0;
    qcompute(0, sa);

    for (int k = 0; k < TPB; ++k) {
        // ---- FIFO head: x rows for this wave's window + a for tile k+1 ----
        f4 xv[16];                         // static indexing only
        {
            const int jbase = (tile0 + k) * JT + jw + (jh << 4);
#pragma unroll
            for (int q = 0; q < 16; ++q) {
                const int j = jbase + q;
                if (j < NN) xv[q] = *(const f4*)(x + (size_t)j * DD + d0);
                else        xv[q] = (f4)(0.0f);
            }
        }
        if (k + 1 < TPB) sa = aload(k + 1);
        SB0;
        // ---- FIFO tail: tile k+2 DMA (survives the whole body in flight) ----
        if (k + 2 < TPB) stage_dma(k + 2);
        SB0;

        // ---- Phase B: acc[r] += qld[r][jj] * x[jj][d0..d0+3] (own wave only) ----
#pragma unroll
        for (int qc = 0; qc < 4; ++qc) {
#pragma unroll
            for (int r = 0; r < RB; ++r) {
                f4 q4 = *(const f4*)&qld[wid][(r << 5) + (jh << 4) + (qc << 2)];
                acc[r] += q4.x * xv[qc * 4 + 0];
                acc[r] += q4.y * xv[qc * 4 + 1];
                acc[r] += q4.z * xv[qc * 4 + 2];
                acc[r] += q4.w * xv[qc * 4 + 3];
            }
        }

        // ---- boundary: wait own tile-k+1 data only; keep k+2 DMAs in flight ----
        if (k + 1 < TPB) {
            if (k + 2 < TPB) { VMCNT8; } else { VMCNT0; }
            SB0;
            qcompute(k + 1, sa);           // wave-private; NO barrier
        }
    }

    // ---- epilogue: fold jh halves, then cross-wave j-window reduction ----
#pragma unroll
    for (int r = 0; r < RB; ++r)
#pragma unroll
        for (int c = 0; c < 4; ++c)
            acc[r][c] += __shfl_xor(acc[r][c], 32);

    __syncthreads();                       // waves done with stg; safe to alias
    float* red = (float*)&stg[0][0][0][0]; // 12 KB scratch
    if (wid > 0 && jh == 0) {
#pragma unroll
        for (int r = 0; r < RB; ++r)
            *(f4*)&red[((wid - 1) * RB + r) * DD + d0] = acc[r];
    }
    __syncthreads();
    if (wid == 0 && jh == 0) {
#pragma unroll
        for (int r = 0; r < RB; ++r) {
            f4 v = acc[r];
#pragma unroll
            for (int p = 0; p < 3; ++p)
                v += *(const f4*)&red[(p * RB + r) * DD + d0];
            *(f4*)&ws[(((size_t)js * RG + rg) * RB + r) * DD + d0] = v;
        }
    }
}

// Kernel 2: out[i,:] = PReLU(sum_js partial[js][i,:]) @ W^T + b
__global__ __launch_bounds__(256, 2)
void prelu_linear(const float* __restrict__ alpha,
                  const float* __restrict__ W,
                  const float* __restrict__ b,
                  const float* __restrict__ ws,
                  float* __restrict__ out)
{
    __shared__ float Wt[128 * 129];
    __shared__ float p[16 * 128];
    const int t  = threadIdx.x;
    const int i0 = blockIdx.x * 16;

#pragma unroll
    for (int it = 0; it < 16; ++it) {
        int f  = (it * 256 + t) * 4;
        int d  = f >> 7;
        int kk = f & 127;
        f4 w4 = *(const f4*)(W + f);
        Wt[(kk + 0) * 129 + d] = w4.x;
        Wt[(kk + 1) * 129 + d] = w4.y;
        Wt[(kk + 2) * 129 + d] = w4.z;
        Wt[(kk + 3) * 129 + d] = w4.w;
    }

#pragma unroll
    for (int it = 0; it < 2; ++it) {
        int fi  = it * 256 + t;
        int row = i0 + (fi >> 5);
        int dc  = (fi & 31) << 2;
        if (row < NN) {
            size_t base = (size_t)row * DD + dc;
            f4 v = *(const f4*)(ws + base);
            v += *(const f4*)(ws + base + (size_t)1 * RG * RB * DD);
            v += *(const f4*)(ws + base + (size_t)2 * RG * RB * DD);
            v += *(const f4*)(ws + base + (size_t)3 * RG * RB * DD);
            f4 al = *(const f4*)(alpha + dc);
            f4 pv;
            pv.x = v.x >= 0.f ? v.x : al.x * v.x;
            pv.y = v.y >= 0.f ? v.y : al.y * v.y;
            pv.z = v.z >= 0.f ? v.z : al.z * v.z;
            pv.w = v.w >= 0.f ? v.w : al.w * v.w;
            *(f4*)&p[(row - i0) * 128 + dc] = pv;
        }
    }
    __syncthreads();

    const int d  = t & 127;
    const int rq = t >> 7;
    const float bv = b[d];
    float acc[8];
#pragma unroll
    for (int ri = 0; ri < 8; ++ri) acc[ri] = 0.f;
#pragma unroll 8
    for (int k = 0; k < 128; ++k) {
        float wv = Wt[k * 129 + d];
#pragma unroll
        for (int ri = 0; ri < 8; ++ri)
            acc[ri] += p[(rq * 8 + ri) * 128 + k] * wv;
    }
#pragma unroll
    for (int ri = 0; ri < 8; ++ri) {
        int row = i0 + rq * 8 + ri;
        if (row < NN) out[(size_t)row * DD + d] = acc[ri] + bv;
    }
}

extern "C" void kernel_launch(void* const* d_in, const int* in_sizes, int n_in,
                              void* d_out, int out_size, void* d_ws, size_t ws_size,
                              hipStream_t stream) {
    const float* theta = (const float*)d_in[0];
    const float* T     = (const float*)d_in[1];
    const float* x     = (const float*)d_in[2];
    const float* a     = (const float*)d_in[3];
    const float* alpha = (const float*)d_in[4];
    const float* W     = (const float*)d_in[5];
    const float* b     = (const float*)d_in[6];
    float* out = (float*)d_out;
    float* ws  = (float*)d_ws;

    dim3 blk(256);
    dim3 g1(RG * JS);                 // 2500 blocks
    diffuse_spmm<<<g1, blk, 0, stream>>>(theta, T, x, a, ws);

    dim3 g2((NN + 15) / 16);          // 313 blocks
    prelu_linear<<<g2, blk, 0, stream>>>(alpha, W, b, ws, out);
}